// Round 6
// baseline (322.861 us; speedup 1.0000x reference)
//
#include <hip/hip_runtime.h>
#include <stdint.h>

// Linformer CMHAttention on MI355X (gfx950).
// B=4,S=4096,C=1024,H=16,D=64,K=256. All matmuls bf16 MFMA 16x16x32, fp32 accum.
// R6: 4-phase column-half pipelined 256x256 GEMM template (quadrant MFMA
//     phases, vmcnt(6) twice per K-tile, ch-split LDS, XOR swizzle both
//     sides); gemm_small rebuilt as 32 b-batched 256x256x4096 GEMMs
//     (split-K x4) on the same template; We/Wf back to bf16 via cvt_wef.

typedef unsigned short u16;
typedef __bf16 bf16t;
typedef bf16t bf16x8 __attribute__((ext_vector_type(8)));
typedef float f32x4 __attribute__((ext_vector_type(4)));
typedef u16 u16x8 __attribute__((ext_vector_type(8)));

#define MFMA16(a, b, c) __builtin_amdgcn_mfma_f32_16x16x32_bf16((a), (b), (c), 0, 0, 0)

__device__ __forceinline__ u16 f2bf(float f) {
  return __builtin_bit_cast(u16, (bf16t)f);  // native RTNE cvt
}

__device__ __forceinline__ bf16x8 ldf(const u16* p) { return *(const bf16x8*)p; }

__device__ __forceinline__ void gload16(const void* g, void* l) {
  __builtin_amdgcn_global_load_lds(
      (__attribute__((address_space(1))) void*)g,
      (__attribute__((address_space(3))) void*)l, 16, 0, 0);
}

// XCD-aware bijective remap (requires nwg % 8 == 0).
__device__ __forceinline__ int xcd_swz(int orig, int nwg) {
  return (orig & 7) * (nwg >> 3) + (orig >> 3);
}

// ================= 256x256 4-phase pipelined bt-GEMM main loop ==============
// C[256][256] tile: A rows (m0..m0+255) x B rows (n0..n0+255), K = 16 tiles
// of 64 starting at kt0. Row address (elements) = base + (row>>6)*s1 +
// (row&63)*s0  (handles (b,d)-interleaved operands; contiguous when s1=64*s0).
// 512 threads, 8 waves 2(M)x4(N), per-wave 128x64 out = acc[8][4].
// LDS 128 KB: [buf][A ch0|A ch1|B ch0|B ch1] of 16 KB each; colhalf ch holds
// k-cols ch*32..+32 as [256 rows][64 B], 16B-slot s at row R holds k-chunk
// s^(R&3) (same XOR on read -> conflict-free; gload writes stay linear).
// Phases per K-tile: q0(mh0,kh0)+stageA0, q1(mh1,kh0)+stageB0,
// q2(mh0,kh1)+stageA1, q3(mh1,kh1)+stageB1; vmcnt(6)+barrier at q0,q2 only
// (3 half-tiles = 6 loads stay in flight across barriers).
__device__ __forceinline__ void gemm256_pipe(const u16* __restrict__ A,
                                             const u16* __restrict__ B,
                                             int m0, int n0, int sA1, int sB1,
                                             int s0, int kt0, f32x4 acc[8][4],
                                             char* smc) {
  const int tid = threadIdx.x;
  const int w = tid >> 6, l = tid & 63, g = l >> 4, r = l & 15;
  const int wr = w >> 2, wc = w & 3;
  const int lrow = l >> 2;                       // 0..15
  const int ksw = (((l & 3) ^ (lrow & 3)) << 4); // staging src swizzle (bytes)
  const int gx = ((g ^ (r & 3)) << 4);           // read-side swizzle (bytes)

  auto stage = [&](const u16* Base, int r0, int s1, int T, int ch, int ldsoff) {
#pragma unroll
    for (int i = 0; i < 2; ++i) {
      const int row = r0 + (w * 2 + i) * 16 + lrow;
      const size_t eoff = (size_t)(row >> 6) * s1 + (size_t)(row & 63) * s0;
      gload16((const char*)Base + eoff * 2 + ((kt0 + T) * 64 + ch * 32) * 2 + ksw,
              smc + ldsoff + (w * 2 + i) * 1024);
    }
  };

  // prologue: tile 0, order ch0A, ch0B, ch1A, ch1B
  stage(A, m0, sA1, 0, 0, 0);
  stage(B, n0, sB1, 0, 0, 32768);
  stage(A, m0, sA1, 0, 1, 16384);
  stage(B, n0, sB1, 0, 1, 32768 + 16384);

  for (int t = 0; t < 16; ++t) {
    const int buf = (t & 1) << 16, nb = buf ^ 65536;
    const int Tn = t < 15 ? t + 1 : 15;
    bf16x8 af[4], bfv[4];

#define QUAD(MH)                                                        \
  __builtin_amdgcn_s_setprio(1);                                        \
  _Pragma("unroll") for (int m = 0; m < 4; ++m)                         \
      _Pragma("unroll") for (int n = 0; n < 4; ++n)                     \
          acc[(MH)*4 + m][n] = MFMA16(af[m], bfv[n], acc[(MH)*4 + m][n]); \
  __builtin_amdgcn_s_setprio(0);

    // ---- q0: (mh0, kh0)
    stage(A, m0, sA1, Tn, 0, nb);
    asm volatile("s_waitcnt vmcnt(6)" ::: "memory");
    __builtin_amdgcn_s_barrier();
    asm volatile("" ::: "memory");
    {
      const char* At = smc + buf;
      const char* Bt = smc + buf + 32768;
#pragma unroll
      for (int n = 0; n < 4; ++n)
        bfv[n] = *(const bf16x8*)(Bt + (wc * 64 + n * 16 + r) * 64 + gx);
#pragma unroll
      for (int m = 0; m < 4; ++m)
        af[m] = *(const bf16x8*)(At + (wr * 128 + m * 16 + r) * 64 + gx);
      QUAD(0)
      // ---- q1: (mh1, kh0)
      stage(B, n0, sB1, Tn, 0, nb + 32768);
#pragma unroll
      for (int m = 0; m < 4; ++m)
        af[m] = *(const bf16x8*)(At + (wr * 128 + 64 + m * 16 + r) * 64 + gx);
      QUAD(1)
    }
    // ---- q2: (mh0, kh1)
    stage(A, m0, sA1, Tn, 1, nb + 16384);
    asm volatile("s_waitcnt vmcnt(6)" ::: "memory");
    __builtin_amdgcn_s_barrier();
    asm volatile("" ::: "memory");
    {
      const char* At = smc + buf + 16384;
      const char* Bt = smc + buf + 32768 + 16384;
#pragma unroll
      for (int n = 0; n < 4; ++n)
        bfv[n] = *(const bf16x8*)(Bt + (wc * 64 + n * 16 + r) * 64 + gx);
#pragma unroll
      for (int m = 0; m < 4; ++m)
        af[m] = *(const bf16x8*)(At + (wr * 128 + m * 16 + r) * 64 + gx);
      QUAD(0)
      // ---- q3: (mh1, kh1)
      stage(B, n0, sB1, Tn, 1, nb + 32768 + 16384);
#pragma unroll
      for (int m = 0; m < 4; ++m)
        af[m] = *(const bf16x8*)(At + (wr * 128 + 64 + m * 16 + r) * 64 + gx);
      QUAD(1)
    }
#undef QUAD
  }
}

// ---------------- f32 -> bf16 conversions (branch-free, 16B/lane) ----------
__global__ __launch_bounds__(256) void cvt_x(const float* __restrict__ src,
                                             u16* __restrict__ dst) {
  const size_t i = ((size_t)blockIdx.x * 256 + threadIdx.x) * 8;
  const float4 a = *(const float4*)(src + i);
  const float4 b = *(const float4*)(src + i + 4);
  u16x8 o;
  o[0] = f2bf(a.x); o[1] = f2bf(a.y); o[2] = f2bf(a.z); o[3] = f2bf(a.w);
  o[4] = f2bf(b.x); o[5] = f2bf(b.y); o[6] = f2bf(b.z); o[7] = f2bf(b.w);
  *(u16x8*)(dst + i) = o;
}

__global__ __launch_bounds__(256) void cvt_w(const float* __restrict__ Wq,
                                             const float* __restrict__ Wk,
                                             const float* __restrict__ Wv,
                                             const float* __restrict__ Wo,
                                             u16* __restrict__ wqkv,
                                             u16* __restrict__ wob) {
  const float* s;
  u16* d;
  switch (blockIdx.y) {
    case 0: s = Wq; d = wqkv; break;
    case 1: s = Wk; d = wqkv + 1048576; break;
    case 2: s = Wv; d = wqkv + 2097152; break;
    default: s = Wo; d = wob; break;
  }
  const size_t i = ((size_t)blockIdx.x * 256 + threadIdx.x) * 8;
  const float4 a = *(const float4*)(s + i);
  const float4 b = *(const float4*)(s + i + 4);
  u16x8 o;
  o[0] = f2bf(a.x); o[1] = f2bf(a.y); o[2] = f2bf(a.z); o[3] = f2bf(a.w);
  o[4] = f2bf(b.x); o[5] = f2bf(b.y); o[6] = f2bf(b.z); o[7] = f2bf(b.w);
  *(u16x8*)(d + i) = o;
}

__global__ __launch_bounds__(256) void cvt_wef(const float* __restrict__ We,
                                               const float* __restrict__ Wf,
                                               u16* __restrict__ web,
                                               u16* __restrict__ wfb) {
  const float* s = blockIdx.y ? Wf : We;
  u16* d = blockIdx.y ? wfb : web;
  const size_t i = ((size_t)blockIdx.x * 256 + threadIdx.x) * 8;
  const float4 a = *(const float4*)(s + i);
  const float4 b = *(const float4*)(s + i + 4);
  u16x8 o;
  o[0] = f2bf(a.x); o[1] = f2bf(a.y); o[2] = f2bf(a.z); o[3] = f2bf(a.w);
  o[4] = f2bf(b.x); o[5] = f2bf(b.y); o[6] = f2bf(b.z); o[7] = f2bf(b.w);
  *(u16x8*)(d + i) = o;
}

// ---------------- Q projection GEMM (scale 1/8 folded in) ----------------
__global__ __launch_bounds__(512, 2) void gemm_q(const u16* __restrict__ A,
                                                 const u16* __restrict__ BT,
                                                 u16* __restrict__ Qd) {
  __shared__ u16 sm[65536];
  const int wg = xcd_swz(blockIdx.x, 256);
  const int m0 = (wg >> 2) * 256, n0 = (wg & 3) * 256;
  const int tid = threadIdx.x, w = tid >> 6, l = tid & 63, g = l >> 4, r = l & 15;
  const int wr = w >> 2, wc = w & 3;
  f32x4 acc[8][4] = {};
  gemm256_pipe(A, BT, m0, n0, 65536, 65536, 1024, 0, acc, (char*)sm);
#pragma unroll
  for (int m = 0; m < 8; ++m)
#pragma unroll
    for (int n = 0; n < 4; ++n)
#pragma unroll
      for (int j = 0; j < 4; ++j) {
        const int mm = m0 + wr * 128 + m * 16 + g * 4 + j;  // (b,s)
        const int nn = n0 + wc * 64 + n * 16 + r;           // (h,d)
        const int b = mm >> 12, s = mm & 4095, h = nn >> 6, d = nn & 63;
        Qd[(((size_t)(b * 16 + h)) * 4096 + s) * 64 + d] = f2bf(acc[m][n][j] * 0.125f);
      }
}

// ---------------- K/V transposed projection GEMM ----------------
__global__ __launch_bounds__(512, 2) void gemm_kv(const u16* __restrict__ A,
                                                  const u16* __restrict__ BT,
                                                  u16* __restrict__ KTd,
                                                  u16* __restrict__ VTd) {
  __shared__ u16 sm[65536];
  const int wg = xcd_swz(blockIdx.x, 512);
  const int m0 = (wg & 7) * 256, n0 = (wg >> 3) * 256;
  const int tid = threadIdx.x, w = tid >> 6, l = tid & 63, g = l >> 4, r = l & 15;
  const int wr = w >> 2, wc = w & 3;
  f32x4 acc[8][4] = {};
  gemm256_pipe(A, BT, m0, n0, 65536, 65536, 1024, 0, acc, (char*)sm);
#pragma unroll
  for (int m = 0; m < 8; ++m)
#pragma unroll
    for (int n = 0; n < 4; ++n)
#pragma unroll
      for (int j = 0; j < 4; ++j) {
        const int mm = m0 + wr * 128 + m * 16 + g * 4 + j;  // (which,h,d)
        const int nn = n0 + wc * 64 + n * 16 + r;           // (b,s)
        const int which = mm >> 10, hd = mm & 1023, h = hd >> 6, d = hd & 63;
        const int b = nn >> 12, s = nn & 4095;
        u16* dst = which ? VTd : KTd;
        dst[(((size_t)(b * 16 + h)) * 64 + d) * 4096 + s] = f2bf(acc[m][n][j]);
      }
}

// ---------------- final output projection ----------------
__global__ __launch_bounds__(512, 2) void gemm_out(const u16* __restrict__ A,
                                                   const u16* __restrict__ BT,
                                                   const float* __restrict__ bo,
                                                   float* __restrict__ out) {
  __shared__ u16 sm[65536];
  const int wg = xcd_swz(blockIdx.x, 256);
  const int m0 = (wg >> 2) * 256, n0 = (wg & 3) * 256;
  const int tid = threadIdx.x, w = tid >> 6, l = tid & 63, g = l >> 4, r = l & 15;
  const int wr = w >> 2, wc = w & 3;
  f32x4 acc[8][4] = {};
  gemm256_pipe(A, BT, m0, n0, 65536, 65536, 1024, 0, acc, (char*)sm);
#pragma unroll
  for (int m = 0; m < 8; ++m)
#pragma unroll
    for (int n = 0; n < 4; ++n)
#pragma unroll
      for (int j = 0; j < 4; ++j) {
        const int mm = m0 + wr * 128 + m * 16 + g * 4 + j;
        const int nn = n0 + wc * 64 + n * 16 + r;
        out[(size_t)mm * 1024 + nn] = acc[m][n][j] + bo[nn];
      }
}

// ---------------- E/F sequence projections (b-batched, split-K x4) ----------
// 128 blocks: h = bx&15, mode = (bx>>4)&1, chunk = bx>>5.
// mode0: part[m=k(256)][n=(b,d)(256)] = We[h] x KT-rows(b,d), K-slice chunk.
// mode1: part[m=(b,d)][n=k] = VT-rows(b,d) x Wf[h].
__global__ __launch_bounds__(512, 2) void gemm_small(const u16* __restrict__ web,
                                                     const u16* __restrict__ wfb,
                                                     const u16* __restrict__ KT,
                                                     const u16* __restrict__ VT,
                                                     float* __restrict__ part) {
  __shared__ u16 sm[65536];
  const int bx = blockIdx.x;
  const int h = bx & 15, mode = (bx >> 4) & 1, chunk = bx >> 5;
  const u16 *Ab, *Bb;
  int sA1, sB1;
  if (mode == 0) {
    Ab = web + (size_t)h * 1048576; sA1 = 262144;
    Bb = KT + (size_t)h * 262144;   sB1 = 4194304;
  } else {
    Ab = VT + (size_t)h * 262144;   sA1 = 4194304;
    Bb = wfb + (size_t)h * 1048576; sB1 = 262144;
  }
  f32x4 acc[8][4] = {};
  gemm256_pipe(Ab, Bb, 0, 0, sA1, sB1, 4096, chunk * 16, acc, (char*)sm);
  float* Cp = part + ((size_t)((mode * 4 + chunk) * 16 + h)) * 65536;
  const int tid = threadIdx.x, w = tid >> 6, l = tid & 63, g = l >> 4, r = l & 15;
  const int wr = w >> 2, wc = w & 3;
#pragma unroll
  for (int m = 0; m < 8; ++m)
#pragma unroll
    for (int n = 0; n < 4; ++n)
#pragma unroll
      for (int j = 0; j < 4; ++j)
        Cp[(size_t)(wr * 128 + m * 16 + g * 4 + j) * 256 + wc * 64 + n * 16 + r] =
            acc[m][n][j];
}

// ---------------- reduce split-K partials -> bf16 Kp / VpT ----------------
// part[p][65536], p = (mode*4+chunk)*16+h. 524288 float4 groups total.
__global__ __launch_bounds__(256) void reduce_small(const float* __restrict__ part,
                                                    u16* __restrict__ Kp,
                                                    u16* __restrict__ VpT) {
  const int i = blockIdx.x * 256 + threadIdx.x;  // 0..524287
  const int mode = i >> 18;
  const int rem = i & 262143;
  const int h = rem >> 14;
  const int e = (rem & 16383) * 4;
  const int m = e >> 8, n = e & 255;
  const float* pb = part + ((size_t)mode * 64 + h) * 65536 + e;
  const float4 s0 = *(const float4*)(pb);
  const float4 s1 = *(const float4*)(pb + 1048576);
  const float4 s2 = *(const float4*)(pb + 2097152);
  const float4 s3 = *(const float4*)(pb + 3145728);
  ushort4 o;
  o.x = f2bf(s0.x + s1.x + s2.x + s3.x);
  o.y = f2bf(s0.y + s1.y + s2.y + s3.y);
  o.z = f2bf(s0.z + s1.z + s2.z + s3.z);
  o.w = f2bf(s0.w + s1.w + s2.w + s3.w);
  if (mode == 0) {
    const int b = n >> 6, d = n & 63;
    *(ushort4*)(Kp + ((size_t)(b * 16 + h)) * 16384 + m * 64 + d) = o;
  } else {
    const int b = m >> 6, d = m & 63;
    *(ushort4*)(VpT + ((size_t)(b * 16 + h)) * 16384 + d * 256 + n) = o;
  }
}

// ---------------- fused scores + softmax + PV ----------------
__global__ __launch_bounds__(256, 1) void attn_fused(const u16* __restrict__ Q,
                                                     const u16* __restrict__ Kp,
                                                     const u16* __restrict__ VpT,
                                                     u16* __restrict__ att) {
  __shared__ u16 P[4][16 * 264];
  const int gid = blockIdx.x;
  const int bh = gid >> 3;
  const int st = gid & 7;
  const int hh = bh & 15, b = bh >> 4;
  const int tid = threadIdx.x, w = tid >> 6, l = tid & 63, g = l >> 4, r = l & 15;
  const u16* Kpb = Kp + (size_t)bh * 256 * 64;
  const u16* Vb = VpT + (size_t)bh * 64 * 256;

  bf16x8 kf[32];
  bf16x8 vf[32];
#pragma unroll
  for (int fn = 0; fn < 16; ++fn) {
    kf[fn * 2 + 0] = ldf(Kpb + (fn * 16 + r) * 64 + g * 8);
    kf[fn * 2 + 1] = ldf(Kpb + (fn * 16 + r) * 64 + 32 + g * 8);
  }
#pragma unroll
  for (int fn2 = 0; fn2 < 4; ++fn2)
#pragma unroll
    for (int kk = 0; kk < 8; ++kk)
      vf[fn2 * 8 + kk] = ldf(Vb + (fn2 * 16 + r) * 256 + kk * 32 + g * 8);

  u16* Pw = P[w];
  for (int t = 0; t < 8; ++t) {
    const int s0 = st * 512 + t * 64 + w * 16;
    const u16* Qb = Q + ((size_t)bh * 4096 + s0) * 64;
    const bf16x8 qf0 = ldf(Qb + r * 64 + g * 8);
    const bf16x8 qf1 = ldf(Qb + r * 64 + 32 + g * 8);
    f32x4 sc[16];
#pragma unroll
    for (int fn = 0; fn < 16; ++fn) {
      sc[fn] = MFMA16(qf0, kf[fn * 2 + 0], (f32x4){});
      sc[fn] = MFMA16(qf1, kf[fn * 2 + 1], sc[fn]);
    }
    float rinv[4];
#pragma unroll
    for (int j = 0; j < 4; ++j) {
      float sum = 0.f;
#pragma unroll
      for (int fn = 0; fn < 16; ++fn) {
        const float e = __expf(sc[fn][j]);
        sc[fn][j] = e;
        sum += e;
      }
      sum += __shfl_xor(sum, 1);
      sum += __shfl_xor(sum, 2);
      sum += __shfl_xor(sum, 4);
      sum += __shfl_xor(sum, 8);
      rinv[j] = 1.0f / sum;
    }
#pragma unroll
    for (int fn = 0; fn < 16; ++fn)
#pragma unroll
      for (int j = 0; j < 4; ++j)
        Pw[(g * 4 + j) * 264 + fn * 16 + r] = f2bf(sc[fn][j]);

    f32x4 o[4] = {};
#pragma unroll
    for (int kk = 0; kk < 8; ++kk) {
      const bf16x8 pa = ldf(Pw + r * 264 + kk * 32 + g * 8);
#pragma unroll
      for (int fn2 = 0; fn2 < 4; ++fn2)
        o[fn2] = MFMA16(pa, vf[fn2 * 8 + kk], o[fn2]);
    }
#pragma unroll
    for (int fn2 = 0; fn2 < 4; ++fn2)
#pragma unroll
      for (int j = 0; j < 4; ++j) {
        const int s = s0 + g * 4 + j;
        const int d = fn2 * 16 + r;
        att[((size_t)b * 4096 + s) * 1024 + hh * 64 + d] = f2bf(o[fn2][j] * rinv[j]);
      }
  }
}

extern "C" void kernel_launch(void* const* d_in, const int* in_sizes, int n_in,
                              void* d_out, int out_size, void* d_ws, size_t ws_size,
                              hipStream_t stream) {
  (void)in_sizes; (void)n_in; (void)out_size; (void)ws_size;
  const float* x  = (const float*)d_in[0];
  const float* Wq = (const float*)d_in[1];
  const float* Wk = (const float*)d_in[2];
  const float* Wv = (const float*)d_in[3];
  const float* We = (const float*)d_in[4];
  const float* Wf = (const float*)d_in[5];
  const float* Wo = (const float*)d_in[6];
  const float* bo = (const float*)d_in[7];
  char* ws = (char*)d_ws;
  u16* xb    = (u16*)(ws + 0);           // x bf16 [16384][1024]    (33,554,432)
  float* prt = (float*)(ws + 0);         // alias: split-K partials (after gemms)
  u16* att   = (u16*)(ws + 0);           // alias: attn output (after reduce)
  u16* wqkv  = (u16*)(ws + 33554432);    // Wq|Wk|Wv [3072][1024]   (6,291,456)
  u16* web   = (u16*)(ws + 39845888);    // We bf16 [16][256][4096] (33,554,432)
  u16* wfb   = (u16*)(ws + 73400320);    // Wf bf16                 (33,554,432)
  u16* wob   = (u16*)(ws + 106954752);   // Wo [1024][1024]         (2,097,152)
  u16* Qd    = (u16*)(ws + 109051904);   // Q/8 [64][4096][64]      (33,554,432)
  u16* KTd   = (u16*)(ws + 142606336);   // K^T [64][64][4096]      (33,554,432)
  u16* VTd   = (u16*)(ws + 176160768);   // V^T [64][64][4096]      (33,554,432)
  u16* Kpd   = (u16*)(ws + 209715200);   // Kp_t [64][256][64]      (2,097,152)
  u16* VpTd  = (u16*)(ws + 211812352);   // VpT  [64][64][256]      (2,097,152)

  cvt_x<<<8192, 256, 0, stream>>>(x, xb);
  cvt_w<<<dim3(512, 4), 256, 0, stream>>>(Wq, Wk, Wv, Wo, wqkv, wob);
  cvt_wef<<<dim3(8192, 2), 256, 0, stream>>>(We, Wf, web, wfb);
  gemm_q<<<256, 512, 0, stream>>>(xb, wqkv, Qd);
  gemm_kv<<<512, 512, 0, stream>>>(wqkv + 1048576, xb, KTd, VTd);
  gemm_small<<<128, 512, 0, stream>>>(web, wfb, KTd, VTd, prt);
  reduce_small<<<2048, 256, 0, stream>>>(prt, Kpd, VpTd);
  attn_fused<<<512, 256, 0, stream>>>(Qd, Kpd, VpTd, att);
  gemm_out<<<256, 512, 0, stream>>>(att, wob, bo, (float*)d_out);
}

// Round 7
// 321.961 us; speedup vs baseline: 1.0028x; 1.0028x over previous
//
#include <hip/hip_runtime.h>
#include <stdint.h>

// Linformer CMHAttention on MI355X (gfx950).
// B=4,S=4096,C=1024,H=16,D=64,K=256. All matmuls bf16 MFMA 16x16x32, fp32 accum.
// R7: fix 4-phase swizzle (slot XOR uses row bits 1-2, not 0-1) -> conflict-free
//     ds_read_b128. Everything else identical to R6.

typedef unsigned short u16;
typedef __bf16 bf16t;
typedef bf16t bf16x8 __attribute__((ext_vector_type(8)));
typedef float f32x4 __attribute__((ext_vector_type(4)));
typedef u16 u16x8 __attribute__((ext_vector_type(8)));

#define MFMA16(a, b, c) __builtin_amdgcn_mfma_f32_16x16x32_bf16((a), (b), (c), 0, 0, 0)

__device__ __forceinline__ u16 f2bf(float f) {
  return __builtin_bit_cast(u16, (bf16t)f);  // native RTNE cvt
}

__device__ __forceinline__ bf16x8 ldf(const u16* p) { return *(const bf16x8*)p; }

__device__ __forceinline__ void gload16(const void* g, void* l) {
  __builtin_amdgcn_global_load_lds(
      (__attribute__((address_space(1))) void*)g,
      (__attribute__((address_space(3))) void*)l, 16, 0, 0);
}

// XCD-aware bijective remap (requires nwg % 8 == 0).
__device__ __forceinline__ int xcd_swz(int orig, int nwg) {
  return (orig & 7) * (nwg >> 3) + (orig >> 3);
}

// ================= 256x256 4-phase pipelined bt-GEMM main loop ==============
// C[256][256] tile: A rows (m0..m0+255) x B rows (n0..n0+255), K = 16 tiles
// of 64 starting at kt0. Row address (elements) = base + (row>>6)*s1 +
// (row&63)*s0  (handles (b,d)-interleaved operands; contiguous when s1=64*s0).
// 512 threads, 8 waves 2(M)x4(N), per-wave 128x64 out = acc[8][4].
// LDS 128 KB: [buf][A ch0|A ch1|B ch0|B ch1] of 16 KB each; colhalf ch holds
// k-cols ch*32..+32 as [256 rows][64 B]; 16B-slot s at row R holds k-chunk
// s^((R>>1)&3)  (injective over (R&1, slot) -> conflict-free b128 reads; the
// same XOR applied on read; gload LDS writes stay linear).
// Phases per K-tile: q0(mh0,kh0)+stageA0, q1(mh1,kh0)+stageB0,
// q2(mh0,kh1)+stageA1, q3(mh1,kh1)+stageB1; vmcnt(6)+barrier at q0,q2 only
// (3 half-tiles = 6 loads stay in flight across barriers).
__device__ __forceinline__ void gemm256_pipe(const u16* __restrict__ A,
                                             const u16* __restrict__ B,
                                             int m0, int n0, int sA1, int sB1,
                                             int s0, int kt0, f32x4 acc[8][4],
                                             char* smc) {
  const int tid = threadIdx.x;
  const int w = tid >> 6, l = tid & 63, g = l >> 4, r = l & 15;
  const int wr = w >> 2, wc = w & 3;
  const int lrow = l >> 2;                            // 0..15
  const int ksw = (((l & 3) ^ ((l >> 3) & 3)) << 4);  // staging src swizzle (bytes)
  const int gx = ((g ^ ((r >> 1) & 3)) << 4);         // read-side swizzle (bytes)

  auto stage = [&](const u16* Base, int r0, int s1, int T, int ch, int ldsoff) {
#pragma unroll
    for (int i = 0; i < 2; ++i) {
      const int row = r0 + (w * 2 + i) * 16 + lrow;
      const size_t eoff = (size_t)(row >> 6) * s1 + (size_t)(row & 63) * s0;
      gload16((const char*)Base + eoff * 2 + ((kt0 + T) * 64 + ch * 32) * 2 + ksw,
              smc + ldsoff + (w * 2 + i) * 1024);
    }
  };

  // prologue: tile 0, order ch0A, ch0B, ch1A, ch1B
  stage(A, m0, sA1, 0, 0, 0);
  stage(B, n0, sB1, 0, 0, 32768);
  stage(A, m0, sA1, 0, 1, 16384);
  stage(B, n0, sB1, 0, 1, 32768 + 16384);

  for (int t = 0; t < 16; ++t) {
    const int buf = (t & 1) << 16, nb = buf ^ 65536;
    const int Tn = t < 15 ? t + 1 : 15;
    bf16x8 af[4], bfv[4];

#define QUAD(MH)                                                        \
  __builtin_amdgcn_s_setprio(1);                                        \
  _Pragma("unroll") for (int m = 0; m < 4; ++m)                         \
      _Pragma("unroll") for (int n = 0; n < 4; ++n)                     \
          acc[(MH)*4 + m][n] = MFMA16(af[m], bfv[n], acc[(MH)*4 + m][n]); \
  __builtin_amdgcn_s_setprio(0);

    // ---- q0: (mh0, kh0)
    stage(A, m0, sA1, Tn, 0, nb);
    asm volatile("s_waitcnt vmcnt(6)" ::: "memory");
    __builtin_amdgcn_s_barrier();
    asm volatile("" ::: "memory");
    {
      const char* At = smc + buf;
      const char* Bt = smc + buf + 32768;
#pragma unroll
      for (int n = 0; n < 4; ++n)
        bfv[n] = *(const bf16x8*)(Bt + (wc * 64 + n * 16 + r) * 64 + gx);
#pragma unroll
      for (int m = 0; m < 4; ++m)
        af[m] = *(const bf16x8*)(At + (wr * 128 + m * 16 + r) * 64 + gx);
      QUAD(0)
      // ---- q1: (mh1, kh0)
      stage(B, n0, sB1, Tn, 0, nb + 32768);
#pragma unroll
      for (int m = 0; m < 4; ++m)
        af[m] = *(const bf16x8*)(At + (wr * 128 + 64 + m * 16 + r) * 64 + gx);
      QUAD(1)
    }
    // ---- q2: (mh0, kh1)
    stage(A, m0, sA1, Tn, 1, nb + 16384);
    asm volatile("s_waitcnt vmcnt(6)" ::: "memory");
    __builtin_amdgcn_s_barrier();
    asm volatile("" ::: "memory");
    {
      const char* At = smc + buf + 16384;
      const char* Bt = smc + buf + 32768 + 16384;
#pragma unroll
      for (int n = 0; n < 4; ++n)
        bfv[n] = *(const bf16x8*)(Bt + (wc * 64 + n * 16 + r) * 64 + gx);
#pragma unroll
      for (int m = 0; m < 4; ++m)
        af[m] = *(const bf16x8*)(At + (wr * 128 + m * 16 + r) * 64 + gx);
      QUAD(0)
      // ---- q3: (mh1, kh1)
      stage(B, n0, sB1, Tn, 1, nb + 32768 + 16384);
#pragma unroll
      for (int m = 0; m < 4; ++m)
        af[m] = *(const bf16x8*)(At + (wr * 128 + 64 + m * 16 + r) * 64 + gx);
      QUAD(1)
    }
#undef QUAD
  }
}

// ---------------- f32 -> bf16 conversions (branch-free, 16B/lane) ----------
__global__ __launch_bounds__(256) void cvt_x(const float* __restrict__ src,
                                             u16* __restrict__ dst) {
  const size_t i = ((size_t)blockIdx.x * 256 + threadIdx.x) * 8;
  const float4 a = *(const float4*)(src + i);
  const float4 b = *(const float4*)(src + i + 4);
  u16x8 o;
  o[0] = f2bf(a.x); o[1] = f2bf(a.y); o[2] = f2bf(a.z); o[3] = f2bf(a.w);
  o[4] = f2bf(b.x); o[5] = f2bf(b.y); o[6] = f2bf(b.z); o[7] = f2bf(b.w);
  *(u16x8*)(dst + i) = o;
}

__global__ __launch_bounds__(256) void cvt_w(const float* __restrict__ Wq,
                                             const float* __restrict__ Wk,
                                             const float* __restrict__ Wv,
                                             const float* __restrict__ Wo,
                                             u16* __restrict__ wqkv,
                                             u16* __restrict__ wob) {
  const float* s;
  u16* d;
  switch (blockIdx.y) {
    case 0: s = Wq; d = wqkv; break;
    case 1: s = Wk; d = wqkv + 1048576; break;
    case 2: s = Wv; d = wqkv + 2097152; break;
    default: s = Wo; d = wob; break;
  }
  const size_t i = ((size_t)blockIdx.x * 256 + threadIdx.x) * 8;
  const float4 a = *(const float4*)(s + i);
  const float4 b = *(const float4*)(s + i + 4);
  u16x8 o;
  o[0] = f2bf(a.x); o[1] = f2bf(a.y); o[2] = f2bf(a.z); o[3] = f2bf(a.w);
  o[4] = f2bf(b.x); o[5] = f2bf(b.y); o[6] = f2bf(b.z); o[7] = f2bf(b.w);
  *(u16x8*)(d + i) = o;
}

__global__ __launch_bounds__(256) void cvt_wef(const float* __restrict__ We,
                                               const float* __restrict__ Wf,
                                               u16* __restrict__ web,
                                               u16* __restrict__ wfb) {
  const float* s = blockIdx.y ? Wf : We;
  u16* d = blockIdx.y ? wfb : web;
  const size_t i = ((size_t)blockIdx.x * 256 + threadIdx.x) * 8;
  const float4 a = *(const float4*)(s + i);
  const float4 b = *(const float4*)(s + i + 4);
  u16x8 o;
  o[0] = f2bf(a.x); o[1] = f2bf(a.y); o[2] = f2bf(a.z); o[3] = f2bf(a.w);
  o[4] = f2bf(b.x); o[5] = f2bf(b.y); o[6] = f2bf(b.z); o[7] = f2bf(b.w);
  *(u16x8*)(d + i) = o;
}

// ---------------- Q projection GEMM (scale 1/8 folded in) ----------------
__global__ __launch_bounds__(512, 2) void gemm_q(const u16* __restrict__ A,
                                                 const u16* __restrict__ BT,
                                                 u16* __restrict__ Qd) {
  __shared__ u16 sm[65536];
  const int wg = xcd_swz(blockIdx.x, 256);
  const int m0 = (wg >> 2) * 256, n0 = (wg & 3) * 256;
  const int tid = threadIdx.x, w = tid >> 6, l = tid & 63, g = l >> 4, r = l & 15;
  const int wr = w >> 2, wc = w & 3;
  f32x4 acc[8][4] = {};
  gemm256_pipe(A, BT, m0, n0, 65536, 65536, 1024, 0, acc, (char*)sm);
#pragma unroll
  for (int m = 0; m < 8; ++m)
#pragma unroll
    for (int n = 0; n < 4; ++n)
#pragma unroll
      for (int j = 0; j < 4; ++j) {
        const int mm = m0 + wr * 128 + m * 16 + g * 4 + j;  // (b,s)
        const int nn = n0 + wc * 64 + n * 16 + r;           // (h,d)
        const int b = mm >> 12, s = mm & 4095, h = nn >> 6, d = nn & 63;
        Qd[(((size_t)(b * 16 + h)) * 4096 + s) * 64 + d] = f2bf(acc[m][n][j] * 0.125f);
      }
}

// ---------------- K/V transposed projection GEMM ----------------
__global__ __launch_bounds__(512, 2) void gemm_kv(const u16* __restrict__ A,
                                                  const u16* __restrict__ BT,
                                                  u16* __restrict__ KTd,
                                                  u16* __restrict__ VTd) {
  __shared__ u16 sm[65536];
  const int wg = xcd_swz(blockIdx.x, 512);
  const int m0 = (wg & 7) * 256, n0 = (wg >> 3) * 256;
  const int tid = threadIdx.x, w = tid >> 6, l = tid & 63, g = l >> 4, r = l & 15;
  const int wr = w >> 2, wc = w & 3;
  f32x4 acc[8][4] = {};
  gemm256_pipe(A, BT, m0, n0, 65536, 65536, 1024, 0, acc, (char*)sm);
#pragma unroll
  for (int m = 0; m < 8; ++m)
#pragma unroll
    for (int n = 0; n < 4; ++n)
#pragma unroll
      for (int j = 0; j < 4; ++j) {
        const int mm = m0 + wr * 128 + m * 16 + g * 4 + j;  // (which,h,d)
        const int nn = n0 + wc * 64 + n * 16 + r;           // (b,s)
        const int which = mm >> 10, hd = mm & 1023, h = hd >> 6, d = hd & 63;
        const int b = nn >> 12, s = nn & 4095;
        u16* dst = which ? VTd : KTd;
        dst[(((size_t)(b * 16 + h)) * 64 + d) * 4096 + s] = f2bf(acc[m][n][j]);
      }
}

// ---------------- final output projection ----------------
__global__ __launch_bounds__(512, 2) void gemm_out(const u16* __restrict__ A,
                                                   const u16* __restrict__ BT,
                                                   const float* __restrict__ bo,
                                                   float* __restrict__ out) {
  __shared__ u16 sm[65536];
  const int wg = xcd_swz(blockIdx.x, 256);
  const int m0 = (wg >> 2) * 256, n0 = (wg & 3) * 256;
  const int tid = threadIdx.x, w = tid >> 6, l = tid & 63, g = l >> 4, r = l & 15;
  const int wr = w >> 2, wc = w & 3;
  f32x4 acc[8][4] = {};
  gemm256_pipe(A, BT, m0, n0, 65536, 65536, 1024, 0, acc, (char*)sm);
#pragma unroll
  for (int m = 0; m < 8; ++m)
#pragma unroll
    for (int n = 0; n < 4; ++n)
#pragma unroll
      for (int j = 0; j < 4; ++j) {
        const int mm = m0 + wr * 128 + m * 16 + g * 4 + j;
        const int nn = n0 + wc * 64 + n * 16 + r;
        out[(size_t)mm * 1024 + nn] = acc[m][n][j] + bo[nn];
      }
}

// ---------------- E/F sequence projections (b-batched, split-K x4) ----------
// 128 blocks: h = bx&15, mode = (bx>>4)&1, chunk = bx>>5.
// mode0: part[m=k(256)][n=(b,d)(256)] = We[h] x KT-rows(b,d), K-slice chunk.
// mode1: part[m=(b,d)][n=k] = VT-rows(b,d) x Wf[h].
__global__ __launch_bounds__(512, 2) void gemm_small(const u16* __restrict__ web,
                                                     const u16* __restrict__ wfb,
                                                     const u16* __restrict__ KT,
                                                     const u16* __restrict__ VT,
                                                     float* __restrict__ part) {
  __shared__ u16 sm[65536];
  const int bx = blockIdx.x;
  const int h = bx & 15, mode = (bx >> 4) & 1, chunk = bx >> 5;
  const u16 *Ab, *Bb;
  int sA1, sB1;
  if (mode == 0) {
    Ab = web + (size_t)h * 1048576; sA1 = 262144;
    Bb = KT + (size_t)h * 262144;   sB1 = 4194304;
  } else {
    Ab = VT + (size_t)h * 262144;   sA1 = 4194304;
    Bb = wfb + (size_t)h * 1048576; sB1 = 262144;
  }
  f32x4 acc[8][4] = {};
  gemm256_pipe(Ab, Bb, 0, 0, sA1, sB1, 4096, chunk * 16, acc, (char*)sm);
  float* Cp = part + ((size_t)((mode * 4 + chunk) * 16 + h)) * 65536;
  const int tid = threadIdx.x, w = tid >> 6, l = tid & 63, g = l >> 4, r = l & 15;
  const int wr = w >> 2, wc = w & 3;
#pragma unroll
  for (int m = 0; m < 8; ++m)
#pragma unroll
    for (int n = 0; n < 4; ++n)
#pragma unroll
      for (int j = 0; j < 4; ++j)
        Cp[(size_t)(wr * 128 + m * 16 + g * 4 + j) * 256 + wc * 64 + n * 16 + r] =
            acc[m][n][j];
}

// ---------------- reduce split-K partials -> bf16 Kp / VpT ----------------
// part[p][65536], p = (mode*4+chunk)*16+h. 524288 float4 groups total.
__global__ __launch_bounds__(256) void reduce_small(const float* __restrict__ part,
                                                    u16* __restrict__ Kp,
                                                    u16* __restrict__ VpT) {
  const int i = blockIdx.x * 256 + threadIdx.x;  // 0..524287
  const int mode = i >> 18;
  const int rem = i & 262143;
  const int h = rem >> 14;
  const int e = (rem & 16383) * 4;
  const int m = e >> 8, n = e & 255;
  const float* pb = part + ((size_t)mode * 64 + h) * 65536 + e;
  const float4 s0 = *(const float4*)(pb);
  const float4 s1 = *(const float4*)(pb + 1048576);
  const float4 s2 = *(const float4*)(pb + 2097152);
  const float4 s3 = *(const float4*)(pb + 3145728);
  ushort4 o;
  o.x = f2bf(s0.x + s1.x + s2.x + s3.x);
  o.y = f2bf(s0.y + s1.y + s2.y + s3.y);
  o.z = f2bf(s0.z + s1.z + s2.z + s3.z);
  o.w = f2bf(s0.w + s1.w + s2.w + s3.w);
  if (mode == 0) {
    const int b = n >> 6, d = n & 63;
    *(ushort4*)(Kp + ((size_t)(b * 16 + h)) * 16384 + m * 64 + d) = o;
  } else {
    const int b = m >> 6, d = m & 63;
    *(ushort4*)(VpT + ((size_t)(b * 16 + h)) * 16384 + d * 256 + n) = o;
  }
}

// ---------------- fused scores + softmax + PV ----------------
__global__ __launch_bounds__(256, 1) void attn_fused(const u16* __restrict__ Q,
                                                     const u16* __restrict__ Kp,
                                                     const u16* __restrict__ VpT,
                                                     u16* __restrict__ att) {
  __shared__ u16 P[4][16 * 264];
  const int gid = blockIdx.x;
  const int bh = gid >> 3;
  const int st = gid & 7;
  const int hh = bh & 15, b = bh >> 4;
  const int tid = threadIdx.x, w = tid >> 6, l = tid & 63, g = l >> 4, r = l & 15;
  const u16* Kpb = Kp + (size_t)bh * 256 * 64;
  const u16* Vb = VpT + (size_t)bh * 64 * 256;

  bf16x8 kf[32];
  bf16x8 vf[32];
#pragma unroll
  for (int fn = 0; fn < 16; ++fn) {
    kf[fn * 2 + 0] = ldf(Kpb + (fn * 16 + r) * 64 + g * 8);
    kf[fn * 2 + 1] = ldf(Kpb + (fn * 16 + r) * 64 + 32 + g * 8);
  }
#pragma unroll
  for (int fn2 = 0; fn2 < 4; ++fn2)
#pragma unroll
    for (int kk = 0; kk < 8; ++kk)
      vf[fn2 * 8 + kk] = ldf(Vb + (fn2 * 16 + r) * 256 + kk * 32 + g * 8);

  u16* Pw = P[w];
  for (int t = 0; t < 8; ++t) {
    const int s0 = st * 512 + t * 64 + w * 16;
    const u16* Qb = Q + ((size_t)bh * 4096 + s0) * 64;
    const bf16x8 qf0 = ldf(Qb + r * 64 + g * 8);
    const bf16x8 qf1 = ldf(Qb + r * 64 + 32 + g * 8);
    f32x4 sc[16];
#pragma unroll
    for (int fn = 0; fn < 16; ++fn) {
      sc[fn] = MFMA16(qf0, kf[fn * 2 + 0], (f32x4){});
      sc[fn] = MFMA16(qf1, kf[fn * 2 + 1], sc[fn]);
    }
    float rinv[4];
#pragma unroll
    for (int j = 0; j < 4; ++j) {
      float sum = 0.f;
#pragma unroll
      for (int fn = 0; fn < 16; ++fn) {
        const float e = __expf(sc[fn][j]);
        sc[fn][j] = e;
        sum += e;
      }
      sum += __shfl_xor(sum, 1);
      sum += __shfl_xor(sum, 2);
      sum += __shfl_xor(sum, 4);
      sum += __shfl_xor(sum, 8);
      rinv[j] = 1.0f / sum;
    }
#pragma unroll
    for (int fn = 0; fn < 16; ++fn)
#pragma unroll
      for (int j = 0; j < 4; ++j)
        Pw[(g * 4 + j) * 264 + fn * 16 + r] = f2bf(sc[fn][j]);

    f32x4 o[4] = {};
#pragma unroll
    for (int kk = 0; kk < 8; ++kk) {
      const bf16x8 pa = ldf(Pw + r * 264 + kk * 32 + g * 8);
#pragma unroll
      for (int fn2 = 0; fn2 < 4; ++fn2)
        o[fn2] = MFMA16(pa, vf[fn2 * 8 + kk], o[fn2]);
    }
#pragma unroll
    for (int fn2 = 0; fn2 < 4; ++fn2)
#pragma unroll
      for (int j = 0; j < 4; ++j) {
        const int s = s0 + g * 4 + j;
        const int d = fn2 * 16 + r;
        att[((size_t)b * 4096 + s) * 1024 + hh * 64 + d] = f2bf(o[fn2][j] * rinv[j]);
      }
  }
}

extern "C" void kernel_launch(void* const* d_in, const int* in_sizes, int n_in,
                              void* d_out, int out_size, void* d_ws, size_t ws_size,
                              hipStream_t stream) {
  (void)in_sizes; (void)n_in; (void)out_size; (void)ws_size;
  const float* x  = (const float*)d_in[0];
  const float* Wq = (const float*)d_in[1];
  const float* Wk = (const float*)d_in[2];
  const float* Wv = (const float*)d_in[3];
  const float* We = (const float*)d_in[4];
  const float* Wf = (const float*)d_in[5];
  const float* Wo = (const float*)d_in[6];
  const float* bo = (const float*)d_in[7];
  char* ws = (char*)d_ws;
  u16* xb    = (u16*)(ws + 0);           // x bf16 [16384][1024]    (33,554,432)
  float* prt = (float*)(ws + 0);         // alias: split-K partials (after gemms)
  u16* att   = (u16*)(ws + 0);           // alias: attn output (after reduce)
  u16* wqkv  = (u16*)(ws + 33554432);    // Wq|Wk|Wv [3072][1024]   (6,291,456)
  u16* web   = (u16*)(ws + 39845888);    // We bf16 [16][256][4096] (33,554,432)
  u16* wfb   = (u16*)(ws + 73400320);    // Wf bf16                 (33,554,432)
  u16* wob   = (u16*)(ws + 106954752);   // Wo [1024][1024]         (2,097,152)
  u16* Qd    = (u16*)(ws + 109051904);   // Q/8 [64][4096][64]      (33,554,432)
  u16* KTd   = (u16*)(ws + 142606336);   // K^T [64][64][4096]      (33,554,432)
  u16* VTd   = (u16*)(ws + 176160768);   // V^T [64][64][4096]      (33,554,432)
  u16* Kpd   = (u16*)(ws + 209715200);   // Kp_t [64][256][64]      (2,097,152)
  u16* VpTd  = (u16*)(ws + 211812352);   // VpT  [64][64][256]      (2,097,152)

  cvt_x<<<8192, 256, 0, stream>>>(x, xb);
  cvt_w<<<dim3(512, 4), 256, 0, stream>>>(Wq, Wk, Wv, Wo, wqkv, wob);
  cvt_wef<<<dim3(8192, 2), 256, 0, stream>>>(We, Wf, web, wfb);
  gemm_q<<<256, 512, 0, stream>>>(xb, wqkv, Qd);
  gemm_kv<<<512, 512, 0, stream>>>(wqkv + 1048576, xb, KTd, VTd);
  gemm_small<<<128, 512, 0, stream>>>(web, wfb, KTd, VTd, prt);
  reduce_small<<<2048, 256, 0, stream>>>(prt, Kpd, VpTd);
  attn_fused<<<512, 256, 0, stream>>>(Qd, Kpd, VpTd, att);
  gemm_out<<<256, 512, 0, stream>>>(att, wob, bo, (float*)d_out);
}